// Round 1
// baseline (2820.909 us; speedup 1.0000x reference)
//
#include <hip/hip_runtime.h>

#define NFEAT 256
#define NHID  128

// ---------------------------------------------------------------------------
// Kernel 1: support = x @ W   (fp32, vector ALU — no fp32 MFMA on CDNA4)
// Block: 256 threads; each block computes a 64-row x 128-col tile.
// Thread t: lane32 = t&31 owns 4 consecutive hid columns (float4),
//           rowgrp = t>>5 owns 8 rows.  x tile staged in LDS (64 KB),
//           W streamed from L2 (128 KB, fully L2-resident).
// ---------------------------------------------------------------------------
__global__ __launch_bounds__(256) void gemm_kernel(
    const float* __restrict__ x, const float* __restrict__ W,
    float* __restrict__ support, int n_nodes) {
  __shared__ float xs[64 * NFEAT];  // 64 KB
  const int t = threadIdx.x;
  const int lane32 = t & 31;   // hid4 index: columns lane32*4 .. +3
  const int rowgrp = t >> 5;   // 0..7, owns rows rowgrp*8 .. +7

  const int rowBase = blockIdx.x * 64;
  if (rowBase >= n_nodes) return;

  // stage 64 rows of x into LDS (float4 coalesced)
  {
    const float4* x4 = (const float4*)x;
    float4* xs4 = (float4*)xs;
    const int maxv = (n_nodes - rowBase) * (NFEAT / 4);
    for (int i = t; i < 64 * (NFEAT / 4); i += 256) {
      float4 v = make_float4(0.f, 0.f, 0.f, 0.f);
      if (i < maxv) v = x4[(size_t)rowBase * (NFEAT / 4) + i];
      xs4[i] = v;
    }
  }
  __syncthreads();

  float4 acc[8];
#pragma unroll
  for (int r = 0; r < 8; ++r) acc[r] = make_float4(0.f, 0.f, 0.f, 0.f);

  const float4* W4 = (const float4*)W;
#pragma unroll 4
  for (int k = 0; k < NFEAT; ++k) {
    const float4 w4 = W4[k * (NHID / 4) + lane32];  // L1/L2 hit, 512B/wave
#pragma unroll
    for (int r = 0; r < 8; ++r) {
      const float xv = xs[(rowgrp * 8 + r) * NFEAT + k];  // LDS broadcast
      acc[r].x += xv * w4.x;
      acc[r].y += xv * w4.y;
      acc[r].z += xv * w4.z;
      acc[r].w += xv * w4.w;
    }
  }

#pragma unroll
  for (int r = 0; r < 8; ++r) {
    const int row = rowBase + rowgrp * 8 + r;
    if (row < n_nodes)
      ((float4*)support)[(size_t)row * (NHID / 4) + lane32] = acc[r];
  }
}

// ---------------------------------------------------------------------------
// Kernel 2: scatter — out[dst] += support[src] * w  (float atomics)
// 32 threads per edge, float4 gather, 4 scalar atomics per thread.
// ---------------------------------------------------------------------------
__global__ __launch_bounds__(256) void scatter_kernel(
    const float* __restrict__ support, const int* __restrict__ esrc,
    const int* __restrict__ edst, const float* __restrict__ ew,
    float* __restrict__ out, int n_edges) {
  const long long idx = (long long)blockIdx.x * 256 + threadIdx.x;
  const int e = (int)(idx >> 5);  // 32 threads per edge
  const int l = (int)(idx & 31);
  if (e >= n_edges) return;
  const int s = esrc[e];
  const int d = edst[e];
  const float wt = ew[e];
  const float4 v = ((const float4*)(support + (size_t)s * NHID))[l];
  float* drow = out + (size_t)d * NHID + l * 4;
  atomicAdd(drow + 0, v.x * wt);
  atomicAdd(drow + 1, v.y * wt);
  atomicAdd(drow + 2, v.z * wt);
  atomicAdd(drow + 3, v.w * wt);
}

// ---------------------------------------------------------------------------
// Kernel 3: out = relu(out + b)   (elementwise, float4)
// ---------------------------------------------------------------------------
__global__ __launch_bounds__(256) void bias_relu_kernel(
    float* __restrict__ out, const float* __restrict__ b, int n4) {
  const int i = blockIdx.x * 256 + threadIdx.x;
  if (i >= n4) return;
  float4 v = ((float4*)out)[i];
  const float4 bb = ((const float4*)b)[i & (NHID / 4 - 1)];
  v.x = fmaxf(v.x + bb.x, 0.f);
  v.y = fmaxf(v.y + bb.y, 0.f);
  v.z = fmaxf(v.z + bb.z, 0.f);
  v.w = fmaxf(v.w + bb.w, 0.f);
  ((float4*)out)[i] = v;
}

extern "C" void kernel_launch(void* const* d_in, const int* in_sizes, int n_in,
                              void* d_out, int out_size, void* d_ws, size_t ws_size,
                              hipStream_t stream) {
  const float* x    = (const float*)d_in[0];
  const int*   esrc = (const int*)d_in[1];
  const int*   edst = (const int*)d_in[2];
  const float* ew   = (const float*)d_in[3];
  const float* W    = (const float*)d_in[4];
  const float* b    = (const float*)d_in[5];
  float* out = (float*)d_out;

  const int n_nodes = in_sizes[0] / NFEAT;
  const int n_edges = in_sizes[1];

  float* support = (float*)d_ws;  // n_nodes*NHID*4 = 51.2 MB

  // zero the accumulation buffer (harness poisons d_out with 0xAA)
  hipMemsetAsync(out, 0, (size_t)n_nodes * NHID * sizeof(float), stream);

  // 1) support = x @ W
  {
    const int grid = (n_nodes + 63) / 64;
    gemm_kernel<<<grid, 256, 0, stream>>>(x, W, support, n_nodes);
  }

  // 2) out[dst] += support[src] * w
  {
    const long long threads = (long long)n_edges * 32;
    const int grid = (int)((threads + 255) / 256);
    scatter_kernel<<<grid, 256, 0, stream>>>(support, esrc, edst, ew, out, n_edges);
  }

  // 3) out = relu(out + b)
  {
    const int n4 = n_nodes * NHID / 4;
    bias_relu_kernel<<<(n4 + 255) / 256, 256, 0, stream>>>(out, b, n4);
  }
}

// Round 2
// 494.795 us; speedup vs baseline: 5.7012x; 5.7012x over previous
//
#include <hip/hip_runtime.h>

#define NFEAT 256
#define NHID  128

// ---------------------------------------------------------------------------
// Kernel 1: support = x @ W   (fp32, vector ALU — no fp32 MFMA on CDNA4)
// ---------------------------------------------------------------------------
__global__ __launch_bounds__(256) void gemm_kernel(
    const float* __restrict__ x, const float* __restrict__ W,
    float* __restrict__ support, int n_nodes) {
  __shared__ float xs[64 * NFEAT];  // 64 KB
  const int t = threadIdx.x;
  const int lane32 = t & 31;
  const int rowgrp = t >> 5;

  const int rowBase = blockIdx.x * 64;
  if (rowBase >= n_nodes) return;

  {
    const float4* x4 = (const float4*)x;
    float4* xs4 = (float4*)xs;
    const int maxv = (n_nodes - rowBase) * (NFEAT / 4);
    for (int i = t; i < 64 * (NFEAT / 4); i += 256) {
      float4 v = make_float4(0.f, 0.f, 0.f, 0.f);
      if (i < maxv) v = x4[(size_t)rowBase * (NFEAT / 4) + i];
      xs4[i] = v;
    }
  }
  __syncthreads();

  float4 acc[8];
#pragma unroll
  for (int r = 0; r < 8; ++r) acc[r] = make_float4(0.f, 0.f, 0.f, 0.f);

  const float4* W4 = (const float4*)W;
#pragma unroll 4
  for (int k = 0; k < NFEAT; ++k) {
    const float4 w4 = W4[k * (NHID / 4) + lane32];
#pragma unroll
    for (int r = 0; r < 8; ++r) {
      const float xv = xs[(rowgrp * 8 + r) * NFEAT + k];
      acc[r].x += xv * w4.x;
      acc[r].y += xv * w4.y;
      acc[r].z += xv * w4.z;
      acc[r].w += xv * w4.w;
    }
  }

#pragma unroll
  for (int r = 0; r < 8; ++r) {
    const int row = rowBase + rowgrp * 8 + r;
    if (row < n_nodes)
      ((float4*)support)[(size_t)row * (NHID / 4) + lane32] = acc[r];
  }
}

// ---------------------------------------------------------------------------
// CSR build: histogram -> hierarchical exclusive scan -> bucket fill
// ---------------------------------------------------------------------------
__global__ __launch_bounds__(256) void count_kernel(
    const int* __restrict__ edst, int* __restrict__ counts, int n_edges) {
  const int e = blockIdx.x * 256 + threadIdx.x;
  if (e < n_edges) atomicAdd(&counts[edst[e]], 1);
}

// 1024 items per block (256 threads x 4), exclusive scan within block.
__global__ __launch_bounds__(256) void scan1_kernel(
    const int* __restrict__ in, int* __restrict__ exc,
    int* __restrict__ bsums, int n) {
  const int tid = threadIdx.x;
  const int lane = tid & 63, wid = tid >> 6;
  const int base = blockIdx.x * 1024 + tid * 4;
  int v0 = 0, v1 = 0, v2 = 0, v3 = 0;
  if (base + 3 < n) {
    int4 v = *(const int4*)(in + base);
    v0 = v.x; v1 = v.y; v2 = v.z; v3 = v.w;
  } else {
    if (base + 0 < n) v0 = in[base + 0];
    if (base + 1 < n) v1 = in[base + 1];
    if (base + 2 < n) v2 = in[base + 2];
  }
  const int tsum = v0 + v1 + v2 + v3;
  int t = tsum;
#pragma unroll
  for (int d = 1; d < 64; d <<= 1) {
    int u = __shfl_up(t, d);
    if (lane >= d) t += u;
  }
  __shared__ int wtot[4], wpre[4];
  if (lane == 63) wtot[wid] = t;
  __syncthreads();
  if (tid == 0) {
    int s = 0;
    for (int w = 0; w < 4; ++w) { wpre[w] = s; s += wtot[w]; }
    bsums[blockIdx.x] = s;
  }
  __syncthreads();
  const int off = (t - tsum) + wpre[wid];
  if (base + 0 < n) exc[base + 0] = off;
  if (base + 1 < n) exc[base + 1] = off + v0;
  if (base + 2 < n) exc[base + 2] = off + v0 + v1;
  if (base + 3 < n) exc[base + 3] = off + v0 + v1 + v2;
}

// single block: exclusive scan of up to 256 block sums (in place)
__global__ __launch_bounds__(256) void scan2_kernel(int* __restrict__ bsums, int nb) {
  const int tid = threadIdx.x;
  const int lane = tid & 63, wid = tid >> 6;
  const int v = (tid < nb) ? bsums[tid] : 0;
  int t = v;
#pragma unroll
  for (int d = 1; d < 64; d <<= 1) {
    int u = __shfl_up(t, d);
    if (lane >= d) t += u;
  }
  __shared__ int wtot[4], wpre[4];
  if (lane == 63) wtot[wid] = t;
  __syncthreads();
  if (tid == 0) {
    int s = 0;
    for (int w = 0; w < 4; ++w) { wpre[w] = s; s += wtot[w]; }
  }
  __syncthreads();
  const int exc = (t - v) + wpre[wid];
  if (tid < nb) bsums[tid] = exc;
}

__global__ __launch_bounds__(256) void scan3_kernel(
    const int* __restrict__ exc, const int* __restrict__ bsums,
    int* __restrict__ row_start, int* __restrict__ cursor, int n, int n_edges) {
  const int i = blockIdx.x * 256 + threadIdx.x;
  if (i < n) {
    const int v = exc[i] + bsums[i >> 10];
    row_start[i] = v;
    cursor[i] = v;
  }
  if (i == 0) row_start[n] = n_edges;
}

__global__ __launch_bounds__(256) void fill_kernel(
    const int* __restrict__ esrc, const int* __restrict__ edst,
    const float* __restrict__ ew, int* __restrict__ cursor,
    int2* __restrict__ packed, int n_edges) {
  const int e = blockIdx.x * 256 + threadIdx.x;
  if (e >= n_edges) return;
  const int d = edst[e];
  const int p = atomicAdd(&cursor[d], 1);
  packed[p] = make_int2(esrc[e], __float_as_int(ew[e]));
}

// ---------------------------------------------------------------------------
// Aggregation: 128 threads per node, one hid column each; gather-sum over
// incoming edges; fused bias + ReLU.
// ---------------------------------------------------------------------------
__global__ __launch_bounds__(256) void agg_kernel(
    const float* __restrict__ support, const int2* __restrict__ packed,
    const int* __restrict__ row_start, const float* __restrict__ bias,
    float* __restrict__ out, int n_nodes) {
  const int node = blockIdx.x * 2 + (threadIdx.x >> 7);
  const int col = threadIdx.x & 127;
  if (node >= n_nodes) return;
  const int start = row_start[node];
  const int end = row_start[node + 1];
  float acc0 = 0.f, acc1 = 0.f;
  int i = start;
  for (; i + 1 < end; i += 2) {
    const int2 e0 = packed[i];
    const int2 e1 = packed[i + 1];
    acc0 += support[(size_t)e0.x * NHID + col] * __int_as_float(e0.y);
    acc1 += support[(size_t)e1.x * NHID + col] * __int_as_float(e1.y);
  }
  if (i < end) {
    const int2 e0 = packed[i];
    acc0 += support[(size_t)e0.x * NHID + col] * __int_as_float(e0.y);
  }
  const float r = acc0 + acc1 + bias[col];
  out[(size_t)node * NHID + col] = fmaxf(r, 0.f);
}

// ---------------------------------------------------------------------------
// Fallback path (if ws too small): atomic scatter, as in round 1
// ---------------------------------------------------------------------------
__global__ __launch_bounds__(256) void scatter_kernel(
    const float* __restrict__ support, const int* __restrict__ esrc,
    const int* __restrict__ edst, const float* __restrict__ ew,
    float* __restrict__ out, int n_edges) {
  const long long idx = (long long)blockIdx.x * 256 + threadIdx.x;
  const int e = (int)(idx >> 5);
  const int l = (int)(idx & 31);
  if (e >= n_edges) return;
  const int s = esrc[e];
  const int d = edst[e];
  const float wt = ew[e];
  const float4 v = ((const float4*)(support + (size_t)s * NHID))[l];
  float* drow = out + (size_t)d * NHID + l * 4;
  atomicAdd(drow + 0, v.x * wt);
  atomicAdd(drow + 1, v.y * wt);
  atomicAdd(drow + 2, v.z * wt);
  atomicAdd(drow + 3, v.w * wt);
}

__global__ __launch_bounds__(256) void bias_relu_kernel(
    float* __restrict__ out, const float* __restrict__ b, int n4) {
  const int i = blockIdx.x * 256 + threadIdx.x;
  if (i >= n4) return;
  float4 v = ((float4*)out)[i];
  const float4 bb = ((const float4*)b)[i & (NHID / 4 - 1)];
  v.x = fmaxf(v.x + bb.x, 0.f);
  v.y = fmaxf(v.y + bb.y, 0.f);
  v.z = fmaxf(v.z + bb.z, 0.f);
  v.w = fmaxf(v.w + bb.w, 0.f);
  ((float4*)out)[i] = v;
}

static inline size_t align_up(size_t v, size_t a) { return (v + a - 1) & ~(a - 1); }

extern "C" void kernel_launch(void* const* d_in, const int* in_sizes, int n_in,
                              void* d_out, int out_size, void* d_ws, size_t ws_size,
                              hipStream_t stream) {
  const float* x    = (const float*)d_in[0];
  const int*   esrc = (const int*)d_in[1];
  const int*   edst = (const int*)d_in[2];
  const float* ew   = (const float*)d_in[3];
  const float* W    = (const float*)d_in[4];
  const float* b    = (const float*)d_in[5];
  float* out = (float*)d_out;

  const int n_nodes = in_sizes[0] / NFEAT;
  const int n_edges = in_sizes[1];

  // workspace layout
  char* ws = (char*)d_ws;
  size_t off = 0;
  float* support = (float*)(ws + off); off = align_up(off + (size_t)n_nodes * NHID * 4, 256);
  int* counts    = (int*)(ws + off);   off = align_up(off + (size_t)n_nodes * 4, 256);
  int* exc       = (int*)(ws + off);   off = align_up(off + (size_t)n_nodes * 4, 256);
  int* bsums     = (int*)(ws + off);   off = align_up(off + 1024 * 4, 256);
  int* row_start = (int*)(ws + off);   off = align_up(off + ((size_t)n_nodes + 1) * 4, 256);
  int* cursor    = (int*)(ws + off);   off = align_up(off + (size_t)n_nodes * 4, 256);
  int2* packed   = (int2*)(ws + off);  off = align_up(off + (size_t)n_edges * 8, 256);
  const bool csr_ok = (off <= ws_size) && (n_nodes <= 256 * 1024);

  // 1) support = x @ W
  gemm_kernel<<<(n_nodes + 63) / 64, 256, 0, stream>>>(x, W, support, n_nodes);

  if (csr_ok) {
    // 2) CSR build
    hipMemsetAsync(counts, 0, (size_t)n_nodes * 4, stream);
    count_kernel<<<(n_edges + 255) / 256, 256, 0, stream>>>(edst, counts, n_edges);
    const int nb = (n_nodes + 1023) / 1024;
    scan1_kernel<<<nb, 256, 0, stream>>>(counts, exc, bsums, n_nodes);
    scan2_kernel<<<1, 256, 0, stream>>>(bsums, nb);
    scan3_kernel<<<(n_nodes + 255) / 256, 256, 0, stream>>>(exc, bsums, row_start, cursor, n_nodes, n_edges);
    fill_kernel<<<(n_edges + 255) / 256, 256, 0, stream>>>(esrc, edst, ew, cursor, packed, n_edges);

    // 3) gather-sum + bias + relu
    agg_kernel<<<(n_nodes + 1) / 2, 256, 0, stream>>>(support, packed, row_start, b, out, n_nodes);
  } else {
    hipMemsetAsync(out, 0, (size_t)n_nodes * NHID * sizeof(float), stream);
    const long long threads = (long long)n_edges * 32;
    scatter_kernel<<<(int)((threads + 255) / 256), 256, 0, stream>>>(support, esrc, edst, ew, out, n_edges);
    const int n4 = n_nodes * NHID / 4;
    bias_relu_kernel<<<(n4 + 255) / 256, 256, 0, stream>>>(out, b, n4);
  }
}

// Round 3
// 233.659 us; speedup vs baseline: 12.0728x; 2.1176x over previous
//
#include <hip/hip_runtime.h>
#include <hip/hip_bf16.h>

#define NFEAT 256
#define NHID  128

typedef short s16x8 __attribute__((ext_vector_type(8)));
typedef float f32x4 __attribute__((ext_vector_type(4)));

static __device__ __forceinline__ ushort bfbits(float f) {
  __hip_bfloat16 h = __float2bfloat16(f);
  return *reinterpret_cast<ushort*>(&h);
}

// ---------------------------------------------------------------------------
// W transpose+convert: Wt[n][k] = bf16(W[k][n])   (one-time, 32K elems)
// ---------------------------------------------------------------------------
__global__ __launch_bounds__(256) void wcvt_kernel(
    const float* __restrict__ W, ushort* __restrict__ Wt) {
  const int id = blockIdx.x * 256 + threadIdx.x;  // grid 128
  const int k = id >> 7, n = id & 127;            // coalesced read of W[k][n]
  Wt[n * NFEAT + k] = bfbits(W[id]);
}

// ---------------------------------------------------------------------------
// MFMA GEMM: support_bf16 = bf16(x @ W).  Block = 256 thr = 4 waves.
// Tile: BM=64 rows x NHID=128 cols; K chunked by 64.  Wave w owns cols
// [w*32, w*32+32).  LDS XOR-swizzle ((row&7)<<4 on byte) kills the
// stride-128B bank conflict on ds_read_b128 (G4 / T2).
// ---------------------------------------------------------------------------
__global__ __launch_bounds__(256) void gemm_mfma(
    const float* __restrict__ x, const ushort* __restrict__ Wt,
    ushort* __restrict__ sup, int n_nodes) {
  __shared__ ushort As[64 * 64];   // [r][k] swizzled, 8 KB
  __shared__ ushort Bs[128 * 64];  // [n][k] swizzled, 16 KB
  const int t = threadIdx.x;
  const int wid = t >> 6;
  const int lane = t & 63;
  const int rowBase = blockIdx.x * 64;

  f32x4 acc[4][2];
#pragma unroll
  for (int m = 0; m < 4; ++m)
#pragma unroll
    for (int n = 0; n < 2; ++n) acc[m][n] = (f32x4){0.f, 0.f, 0.f, 0.f};

  const float4* x4 = (const float4*)x;

  for (int kc = 0; kc < 4; ++kc) {
    __syncthreads();  // protect previous chunk's reads
    // stage A: 64 rows x 64 k (fp32 -> bf16), swizzled
#pragma unroll
    for (int it = 0; it < 4; ++it) {
      const int i4 = t + it * 256;       // float4 index, 0..1023
      const int r = i4 >> 4, k4 = i4 & 15;
      const int row = rowBase + r;
      float4 v = make_float4(0.f, 0.f, 0.f, 0.f);
      if (row < n_nodes) v = x4[(size_t)row * (NFEAT / 4) + kc * 16 + k4];
      ushort4 h;
      h.x = bfbits(v.x); h.y = bfbits(v.y); h.z = bfbits(v.z); h.w = bfbits(v.w);
      int byte = (r << 7) + (k4 << 3);
      byte ^= (r & 7) << 4;
      *(ushort4*)((char*)As + byte) = h;
    }
    // stage B: 128 cols x 64 k from Wt (already bf16), swizzled
#pragma unroll
    for (int it = 0; it < 8; ++it) {
      const int idx = t + it * 256;      // ushort4 index, 0..2047
      const int col = idx >> 4, k4 = idx & 15;
      const ushort4 h = *(const ushort4*)(Wt + col * NFEAT + kc * 64 + k4 * 4);
      int byte = (col << 7) + (k4 << 3);
      byte ^= (col & 7) << 4;
      *(ushort4*)((char*)Bs + byte) = h;
    }
    __syncthreads();
    // 2 k-steps of 32
#pragma unroll
    for (int ks = 0; ks < 2; ++ks) {
      const int k0 = ks * 32 + (lane >> 4) * 8;
      s16x8 af[4], bfr[2];
#pragma unroll
      for (int m = 0; m < 4; ++m) {
        const int r = m * 16 + (lane & 15);
        int byte = (r << 7) + (k0 << 1);
        byte ^= (r & 7) << 4;
        af[m] = *(const s16x8*)((const char*)As + byte);
      }
#pragma unroll
      for (int n = 0; n < 2; ++n) {
        const int c = wid * 32 + n * 16 + (lane & 15);
        int byte = (c << 7) + (k0 << 1);
        byte ^= (c & 7) << 4;
        bfr[n] = *(const s16x8*)((const char*)Bs + byte);
      }
#pragma unroll
      for (int m = 0; m < 4; ++m)
#pragma unroll
        for (int n = 0; n < 2; ++n)
          acc[m][n] = __builtin_amdgcn_mfma_f32_16x16x32_bf16(af[m], bfr[n], acc[m][n], 0, 0, 0);
    }
  }

  // C/D layout: col = lane&15, row = (lane>>4)*4 + reg   [m89-verified]
#pragma unroll
  for (int m = 0; m < 4; ++m) {
#pragma unroll
    for (int rr = 0; rr < 4; ++rr) {
      const int row = rowBase + m * 16 + (lane >> 4) * 4 + rr;
      if (row < n_nodes) {
#pragma unroll
        for (int n = 0; n < 2; ++n) {
          const int col = wid * 32 + n * 16 + (lane & 15);
          sup[(size_t)row * NHID + col] = bfbits(acc[m][n][rr]);
        }
      }
    }
  }
}

// ---------------------------------------------------------------------------
// CSR build: rank-fused histogram -> hierarchical scan -> atomic-free fill
// ---------------------------------------------------------------------------
__global__ __launch_bounds__(256) void count_rank_kernel(
    const int* __restrict__ edst, int* __restrict__ counts,
    int* __restrict__ rank, int n_edges) {
  const int e = blockIdx.x * 256 + threadIdx.x;
  if (e < n_edges) rank[e] = atomicAdd(&counts[edst[e]], 1);
}

__global__ __launch_bounds__(256) void scan1_kernel(
    const int* __restrict__ in, int* __restrict__ exc,
    int* __restrict__ bsums, int n) {
  const int tid = threadIdx.x;
  const int lane = tid & 63, wid = tid >> 6;
  const int base = blockIdx.x * 1024 + tid * 4;
  int v0 = 0, v1 = 0, v2 = 0, v3 = 0;
  if (base + 3 < n) {
    int4 v = *(const int4*)(in + base);
    v0 = v.x; v1 = v.y; v2 = v.z; v3 = v.w;
  } else {
    if (base + 0 < n) v0 = in[base + 0];
    if (base + 1 < n) v1 = in[base + 1];
    if (base + 2 < n) v2 = in[base + 2];
  }
  const int tsum = v0 + v1 + v2 + v3;
  int t = tsum;
#pragma unroll
  for (int d = 1; d < 64; d <<= 1) {
    int u = __shfl_up(t, d);
    if (lane >= d) t += u;
  }
  __shared__ int wtot[4], wpre[4];
  if (lane == 63) wtot[wid] = t;
  __syncthreads();
  if (tid == 0) {
    int s = 0;
    for (int w = 0; w < 4; ++w) { wpre[w] = s; s += wtot[w]; }
    bsums[blockIdx.x] = s;
  }
  __syncthreads();
  const int off = (t - tsum) + wpre[wid];
  if (base + 0 < n) exc[base + 0] = off;
  if (base + 1 < n) exc[base + 1] = off + v0;
  if (base + 2 < n) exc[base + 2] = off + v0 + v1;
  if (base + 3 < n) exc[base + 3] = off + v0 + v1 + v2;
}

__global__ __launch_bounds__(256) void scan2_kernel(int* __restrict__ bsums, int nb) {
  const int tid = threadIdx.x;
  const int lane = tid & 63, wid = tid >> 6;
  const int v = (tid < nb) ? bsums[tid] : 0;
  int t = v;
#pragma unroll
  for (int d = 1; d < 64; d <<= 1) {
    int u = __shfl_up(t, d);
    if (lane >= d) t += u;
  }
  __shared__ int wtot[4], wpre[4];
  if (lane == 63) wtot[wid] = t;
  __syncthreads();
  if (tid == 0) {
    int s = 0;
    for (int w = 0; w < 4; ++w) { wpre[w] = s; s += wtot[w]; }
  }
  __syncthreads();
  const int exc = (t - v) + wpre[wid];
  if (tid < nb) bsums[tid] = exc;
}

__global__ __launch_bounds__(256) void scan3_kernel(
    const int* __restrict__ exc, const int* __restrict__ bsums,
    int* __restrict__ row_start, int n, int n_edges) {
  const int i = blockIdx.x * 256 + threadIdx.x;
  if (i < n) row_start[i] = exc[i] + bsums[i >> 10];
  if (i == 0) row_start[n] = n_edges;
}

__global__ __launch_bounds__(256) void fill_kernel(
    const int* __restrict__ esrc, const int* __restrict__ edst,
    const float* __restrict__ ew, const int* __restrict__ rank,
    const int* __restrict__ row_start, int2* __restrict__ packed, int n_edges) {
  const int e = blockIdx.x * 256 + threadIdx.x;
  if (e >= n_edges) return;
  const int pos = row_start[edst[e]] + rank[e];
  packed[pos] = make_int2(esrc[e], __float_as_int(ew[e]));
}

// ---------------------------------------------------------------------------
// Aggregation over bf16 support: 64 threads/node (2 cols each via ushort2),
// 4 nodes per block; fused bias + ReLU, float2 output write.
// ---------------------------------------------------------------------------
__global__ __launch_bounds__(256) void agg_kernel(
    const ushort* __restrict__ sup, const int2* __restrict__ packed,
    const int* __restrict__ row_start, const float* __restrict__ bias,
    float* __restrict__ out, int n_nodes) {
  const int node = blockIdx.x * 4 + (threadIdx.x >> 6);
  const int c2 = threadIdx.x & 63;
  if (node >= n_nodes) return;
  int i = row_start[node];
  const int end = row_start[node + 1];
  float a0 = 0.f, a1 = 0.f, b0 = 0.f, b1 = 0.f;
  for (; i + 1 < end; i += 2) {
    const int2 e0 = packed[i];
    const int2 e1 = packed[i + 1];
    const uint u0 = *(const uint*)(sup + (size_t)e0.x * NHID + c2 * 2);
    const uint u1 = *(const uint*)(sup + (size_t)e1.x * NHID + c2 * 2);
    const float w0 = __int_as_float(e0.y);
    const float w1 = __int_as_float(e1.y);
    a0 += __uint_as_float(u0 << 16) * w0;
    a1 += __uint_as_float(u0 & 0xffff0000u) * w0;
    b0 += __uint_as_float(u1 << 16) * w1;
    b1 += __uint_as_float(u1 & 0xffff0000u) * w1;
  }
  if (i < end) {
    const int2 e0 = packed[i];
    const uint u0 = *(const uint*)(sup + (size_t)e0.x * NHID + c2 * 2);
    const float w0 = __int_as_float(e0.y);
    a0 += __uint_as_float(u0 << 16) * w0;
    a1 += __uint_as_float(u0 & 0xffff0000u) * w0;
  }
  const float2 bb = ((const float2*)bias)[c2];
  const float r0 = a0 + b0 + bb.x;
  const float r1 = a1 + b1 + bb.y;
  ((float2*)out)[(size_t)node * (NHID / 2) + c2] = make_float2(fmaxf(r0, 0.f), fmaxf(r1, 0.f));
}

// ---------------------------------------------------------------------------
// Fallback (ws too small): atomic scatter over bf16 support
// ---------------------------------------------------------------------------
__global__ __launch_bounds__(256) void scatter_bf16_kernel(
    const ushort* __restrict__ sup, const int* __restrict__ esrc,
    const int* __restrict__ edst, const float* __restrict__ ew,
    float* __restrict__ out, int n_edges) {
  const long long idx = (long long)blockIdx.x * 256 + threadIdx.x;
  const int e = (int)(idx >> 6);
  const int c2 = (int)(idx & 63);
  if (e >= n_edges) return;
  const int s = esrc[e];
  const int d = edst[e];
  const float wt = ew[e];
  const uint u = *(const uint*)(sup + (size_t)s * NHID + c2 * 2);
  float* drow = out + (size_t)d * NHID + c2 * 2;
  atomicAdd(drow + 0, __uint_as_float(u << 16) * wt);
  atomicAdd(drow + 1, __uint_as_float(u & 0xffff0000u) * wt);
}

__global__ __launch_bounds__(256) void bias_relu_kernel(
    float* __restrict__ out, const float* __restrict__ b, int n4) {
  const int i = blockIdx.x * 256 + threadIdx.x;
  if (i >= n4) return;
  float4 v = ((float4*)out)[i];
  const float4 bb = ((const float4*)b)[i & (NHID / 4 - 1)];
  v.x = fmaxf(v.x + bb.x, 0.f);
  v.y = fmaxf(v.y + bb.y, 0.f);
  v.z = fmaxf(v.z + bb.z, 0.f);
  v.w = fmaxf(v.w + bb.w, 0.f);
  ((float4*)out)[i] = v;
}

static inline size_t align_up(size_t v, size_t a) { return (v + a - 1) & ~(a - 1); }

extern "C" void kernel_launch(void* const* d_in, const int* in_sizes, int n_in,
                              void* d_out, int out_size, void* d_ws, size_t ws_size,
                              hipStream_t stream) {
  const float* x    = (const float*)d_in[0];
  const int*   esrc = (const int*)d_in[1];
  const int*   edst = (const int*)d_in[2];
  const float* ew   = (const float*)d_in[3];
  const float* W    = (const float*)d_in[4];
  const float* b    = (const float*)d_in[5];
  float* out = (float*)d_out;

  const int n_nodes = in_sizes[0] / NFEAT;
  const int n_edges = in_sizes[1];

  // workspace layout (~46 MB at N=100k, E=1.6M)
  char* ws = (char*)d_ws;
  size_t off = 0;
  ushort* sup     = (ushort*)(ws + off); off = align_up(off + (size_t)n_nodes * NHID * 2, 256);
  ushort* Wt      = (ushort*)(ws + off); off = align_up(off + (size_t)NFEAT * NHID * 2, 256);
  int* counts     = (int*)(ws + off);    off = align_up(off + (size_t)n_nodes * 4, 256);
  int* exc        = (int*)(ws + off);    off = align_up(off + (size_t)n_nodes * 4, 256);
  int* bsums      = (int*)(ws + off);    off = align_up(off + 1024 * 4, 256);
  int* row_start  = (int*)(ws + off);    off = align_up(off + ((size_t)n_nodes + 1) * 4, 256);
  int* rank       = (int*)(ws + off);    off = align_up(off + (size_t)n_edges * 4, 256);
  int2* packed    = (int2*)(ws + off);   off = align_up(off + (size_t)n_edges * 8, 256);
  const bool csr_ok = (off <= ws_size) && (n_nodes <= 256 * 1024);

  // 1) Wt = bf16(W^T); support = bf16(x @ W) via MFMA
  wcvt_kernel<<<(NFEAT * NHID) / 256, 256, 0, stream>>>(W, Wt);
  gemm_mfma<<<(n_nodes + 63) / 64, 256, 0, stream>>>(x, Wt, sup, n_nodes);

  if (csr_ok) {
    // 2) CSR build (one atomic pass, rank-fused)
    hipMemsetAsync(counts, 0, (size_t)n_nodes * 4, stream);
    count_rank_kernel<<<(n_edges + 255) / 256, 256, 0, stream>>>(edst, counts, rank, n_edges);
    const int nb = (n_nodes + 1023) / 1024;
    scan1_kernel<<<nb, 256, 0, stream>>>(counts, exc, bsums, n_nodes);
    scan2_kernel<<<1, 256, 0, stream>>>(bsums, nb);
    scan3_kernel<<<(n_nodes + 255) / 256, 256, 0, stream>>>(exc, bsums, row_start, n_nodes, n_edges);
    fill_kernel<<<(n_edges + 255) / 256, 256, 0, stream>>>(esrc, edst, ew, rank, row_start, packed, n_edges);

    // 3) gather-sum + bias + relu
    agg_kernel<<<(n_nodes + 3) / 4, 256, 0, stream>>>(sup, packed, row_start, b, out, n_nodes);
  } else {
    hipMemsetAsync(out, 0, (size_t)n_nodes * NHID * sizeof(float), stream);
    const long long threads = (long long)n_edges * 64;
    scatter_bf16_kernel<<<(int)((threads + 255) / 256), 256, 0, stream>>>(sup, esrc, edst, ew, out, n_edges);
    const int n4 = n_nodes * NHID / 4;
    bias_relu_kernel<<<(n4 + 255) / 256, 256, 0, stream>>>(out, b, n4);
  }
}

// Round 4
// 225.431 us; speedup vs baseline: 12.5134x; 1.0365x over previous
//
#include <hip/hip_runtime.h>
#include <hip/hip_bf16.h>

#define NFEAT 256
#define NHID  128

typedef short s16x8 __attribute__((ext_vector_type(8)));
typedef float f32x4 __attribute__((ext_vector_type(4)));
typedef int   i32x2 __attribute__((ext_vector_type(2)));
typedef uint  u32x2 __attribute__((ext_vector_type(2)));

static __device__ __forceinline__ ushort bfbits(float f) {
  __hip_bfloat16 h = __float2bfloat16(f);
  return *reinterpret_cast<ushort*>(&h);
}

// ---------------------------------------------------------------------------
// W transpose+convert: Wt[n][k] = bf16(W[k][n])   (one-time, 32K elems)
// ---------------------------------------------------------------------------
__global__ __launch_bounds__(256) void wcvt_kernel(
    const float* __restrict__ W, ushort* __restrict__ Wt) {
  const int id = blockIdx.x * 256 + threadIdx.x;  // grid 128
  const int k = id >> 7, n = id & 127;            // coalesced read of W[k][n]
  Wt[n * NFEAT + k] = bfbits(W[id]);
}

// ---------------------------------------------------------------------------
// MFMA GEMM: support_bf16 = bf16(x @ W).  Block = 256 thr = 4 waves.
// Tile: BM=64 x NHID=128; K chunked by 64.  LDS XOR-swizzle (T2/G4).
// ---------------------------------------------------------------------------
__global__ __launch_bounds__(256) void gemm_mfma(
    const float* __restrict__ x, const ushort* __restrict__ Wt,
    ushort* __restrict__ sup, int n_nodes) {
  __shared__ ushort As[64 * 64];   // [r][k] swizzled, 8 KB
  __shared__ ushort Bs[128 * 64];  // [n][k] swizzled, 16 KB
  const int t = threadIdx.x;
  const int wid = t >> 6;
  const int lane = t & 63;
  const int rowBase = blockIdx.x * 64;

  f32x4 acc[4][2];
#pragma unroll
  for (int m = 0; m < 4; ++m)
#pragma unroll
    for (int n = 0; n < 2; ++n) acc[m][n] = (f32x4){0.f, 0.f, 0.f, 0.f};

  const float4* x4 = (const float4*)x;

  for (int kc = 0; kc < 4; ++kc) {
    __syncthreads();
#pragma unroll
    for (int it = 0; it < 4; ++it) {
      const int i4 = t + it * 256;
      const int r = i4 >> 4, k4 = i4 & 15;
      const int row = rowBase + r;
      float4 v = make_float4(0.f, 0.f, 0.f, 0.f);
      if (row < n_nodes) v = x4[(size_t)row * (NFEAT / 4) + kc * 16 + k4];
      ushort4 h;
      h.x = bfbits(v.x); h.y = bfbits(v.y); h.z = bfbits(v.z); h.w = bfbits(v.w);
      int byte = (r << 7) + (k4 << 3);
      byte ^= (r & 7) << 4;
      *(ushort4*)((char*)As + byte) = h;
    }
#pragma unroll
    for (int it = 0; it < 8; ++it) {
      const int idx = t + it * 256;
      const int col = idx >> 4, k4 = idx & 15;
      const ushort4 h = *(const ushort4*)(Wt + col * NFEAT + kc * 64 + k4 * 4);
      int byte = (col << 7) + (k4 << 3);
      byte ^= (col & 7) << 4;
      *(ushort4*)((char*)Bs + byte) = h;
    }
    __syncthreads();
#pragma unroll
    for (int ks = 0; ks < 2; ++ks) {
      const int k0 = ks * 32 + (lane >> 4) * 8;
      s16x8 af[4], bfr[2];
#pragma unroll
      for (int m = 0; m < 4; ++m) {
        const int r = m * 16 + (lane & 15);
        int byte = (r << 7) + (k0 << 1);
        byte ^= (r & 7) << 4;
        af[m] = *(const s16x8*)((const char*)As + byte);
      }
#pragma unroll
      for (int n = 0; n < 2; ++n) {
        const int c = wid * 32 + n * 16 + (lane & 15);
        int byte = (c << 7) + (k0 << 1);
        byte ^= (c & 7) << 4;
        bfr[n] = *(const s16x8*)((const char*)Bs + byte);
      }
#pragma unroll
      for (int m = 0; m < 4; ++m)
#pragma unroll
        for (int n = 0; n < 2; ++n)
          acc[m][n] = __builtin_amdgcn_mfma_f32_16x16x32_bf16(af[m], bfr[n], acc[m][n], 0, 0, 0);
    }
  }

  // C/D layout: col = lane&15, row = (lane>>4)*4 + reg   [m89-verified]
#pragma unroll
  for (int m = 0; m < 4; ++m) {
#pragma unroll
    for (int rr = 0; rr < 4; ++rr) {
      const int row = rowBase + m * 16 + (lane >> 4) * 4 + rr;
      if (row < n_nodes) {
#pragma unroll
        for (int n = 0; n < 2; ++n) {
          const int col = wid * 32 + n * 16 + (lane & 15);
          sup[(size_t)row * NHID + col] = bfbits(acc[m][n][rr]);
        }
      }
    }
  }
}

// ---------------------------------------------------------------------------
// CSR build: rank-fused histogram -> hierarchical scan -> atomic-free fill
// ---------------------------------------------------------------------------
__global__ __launch_bounds__(256) void count_rank_kernel(
    const int* __restrict__ edst, int* __restrict__ counts,
    int* __restrict__ rank, int n_edges) {
  const int e = blockIdx.x * 256 + threadIdx.x;
  if (e < n_edges) rank[e] = atomicAdd(&counts[edst[e]], 1);
}

__global__ __launch_bounds__(256) void scan1_kernel(
    const int* __restrict__ in, int* __restrict__ exc,
    int* __restrict__ bsums, int n) {
  const int tid = threadIdx.x;
  const int lane = tid & 63, wid = tid >> 6;
  const int base = blockIdx.x * 1024 + tid * 4;
  int v0 = 0, v1 = 0, v2 = 0, v3 = 0;
  if (base + 3 < n) {
    int4 v = *(const int4*)(in + base);
    v0 = v.x; v1 = v.y; v2 = v.z; v3 = v.w;
  } else {
    if (base + 0 < n) v0 = in[base + 0];
    if (base + 1 < n) v1 = in[base + 1];
    if (base + 2 < n) v2 = in[base + 2];
  }
  const int tsum = v0 + v1 + v2 + v3;
  int t = tsum;
#pragma unroll
  for (int d = 1; d < 64; d <<= 1) {
    int u = __shfl_up(t, d);
    if (lane >= d) t += u;
  }
  __shared__ int wtot[4], wpre[4];
  if (lane == 63) wtot[wid] = t;
  __syncthreads();
  if (tid == 0) {
    int s = 0;
    for (int w = 0; w < 4; ++w) { wpre[w] = s; s += wtot[w]; }
    bsums[blockIdx.x] = s;
  }
  __syncthreads();
  const int off = (t - tsum) + wpre[wid];
  if (base + 0 < n) exc[base + 0] = off;
  if (base + 1 < n) exc[base + 1] = off + v0;
  if (base + 2 < n) exc[base + 2] = off + v0 + v1;
  if (base + 3 < n) exc[base + 3] = off + v0 + v1 + v2;
}

__global__ __launch_bounds__(256) void scan2_kernel(int* __restrict__ bsums, int nb) {
  const int tid = threadIdx.x;
  const int lane = tid & 63, wid = tid >> 6;
  const int v = (tid < nb) ? bsums[tid] : 0;
  int t = v;
#pragma unroll
  for (int d = 1; d < 64; d <<= 1) {
    int u = __shfl_up(t, d);
    if (lane >= d) t += u;
  }
  __shared__ int wtot[4], wpre[4];
  if (lane == 63) wtot[wid] = t;
  __syncthreads();
  if (tid == 0) {
    int s = 0;
    for (int w = 0; w < 4; ++w) { wpre[w] = s; s += wtot[w]; }
  }
  __syncthreads();
  const int exc = (t - v) + wpre[wid];
  if (tid < nb) bsums[tid] = exc;
}

__global__ __launch_bounds__(256) void scan3_kernel(
    const int* __restrict__ exc, const int* __restrict__ bsums,
    int* __restrict__ row_start, int n, int n_edges) {
  const int i = blockIdx.x * 256 + threadIdx.x;
  if (i < n) row_start[i] = exc[i] + bsums[i >> 10];
  if (i == 0) row_start[n] = n_edges;
}

__global__ __launch_bounds__(256) void fill_kernel(
    const int* __restrict__ esrc, const int* __restrict__ edst,
    const float* __restrict__ ew, const int* __restrict__ rank,
    const int* __restrict__ row_start, int2* __restrict__ packed, int n_edges) {
  const int e = blockIdx.x * 256 + threadIdx.x;
  if (e >= n_edges) return;
  const int pos = row_start[edst[e]] + rank[e];
  packed[pos] = make_int2(esrc[e], __float_as_int(ew[e]));
}

// ---------------------------------------------------------------------------
// Aggregation: 1 wave per node; half-wave (32 lanes x 8B) covers a full
// 256B bf16 support row -> an edge PAIR per load; unroll x2 -> 4 edges in
// flight.  NT loads for packed, NT store for out (preserve L2 for gather).
// ---------------------------------------------------------------------------
__global__ __launch_bounds__(256) void agg_kernel(
    const ushort* __restrict__ sup, const i32x2* __restrict__ packed,
    const int* __restrict__ row_start, const float* __restrict__ bias,
    float* __restrict__ out, int n_nodes) {
  const int node = blockIdx.x * 4 + (threadIdx.x >> 6);
  if (node >= n_nodes) return;
  const int lane = threadIdx.x & 63;
  const int half = lane >> 5;   // which edge of the pair
  const int c4 = lane & 31;     // col quad: cols 4*c4 .. 4*c4+3
  const int start = row_start[node];
  const int end = row_start[node + 1];

  float a0 = 0.f, a1 = 0.f, a2 = 0.f, a3 = 0.f;
  int i = start;
  for (; i + 3 < end; i += 4) {
    const i32x2 e0 = __builtin_nontemporal_load(packed + i + half);
    const i32x2 e1 = __builtin_nontemporal_load(packed + i + 2 + half);
    const u32x2 u0 = *(const u32x2*)(sup + (size_t)e0.x * NHID + c4 * 4);
    const u32x2 u1 = *(const u32x2*)(sup + (size_t)e1.x * NHID + c4 * 4);
    const float w0 = __int_as_float(e0.y);
    const float w1 = __int_as_float(e1.y);
    a0 += __uint_as_float(u0.x << 16) * w0 + __uint_as_float(u1.x << 16) * w1;
    a1 += __uint_as_float(u0.x & 0xffff0000u) * w0 + __uint_as_float(u1.x & 0xffff0000u) * w1;
    a2 += __uint_as_float(u0.y << 16) * w0 + __uint_as_float(u1.y << 16) * w1;
    a3 += __uint_as_float(u0.y & 0xffff0000u) * w0 + __uint_as_float(u1.y & 0xffff0000u) * w1;
  }
  for (; i < end; i += 2) {
    if (i + half < end) {
      const i32x2 e0 = __builtin_nontemporal_load(packed + i + half);
      const u32x2 u0 = *(const u32x2*)(sup + (size_t)e0.x * NHID + c4 * 4);
      const float w0 = __int_as_float(e0.y);
      a0 += __uint_as_float(u0.x << 16) * w0;
      a1 += __uint_as_float(u0.x & 0xffff0000u) * w0;
      a2 += __uint_as_float(u0.y << 16) * w0;
      a3 += __uint_as_float(u0.y & 0xffff0000u) * w0;
    }
  }

  a0 += __shfl_xor(a0, 32);
  a1 += __shfl_xor(a1, 32);
  a2 += __shfl_xor(a2, 32);
  a3 += __shfl_xor(a3, 32);

  if (half == 0) {
    const float4 bb = ((const float4*)bias)[c4];
    f32x4 r;
    r.x = fmaxf(a0 + bb.x, 0.f);
    r.y = fmaxf(a1 + bb.y, 0.f);
    r.z = fmaxf(a2 + bb.z, 0.f);
    r.w = fmaxf(a3 + bb.w, 0.f);
    __builtin_nontemporal_store(r, (f32x4*)out + (size_t)node * 32 + c4);
  }
}

// ---------------------------------------------------------------------------
// Fallback (ws too small): atomic scatter over bf16 support
// ---------------------------------------------------------------------------
__global__ __launch_bounds__(256) void scatter_bf16_kernel(
    const ushort* __restrict__ sup, const int* __restrict__ esrc,
    const int* __restrict__ edst, const float* __restrict__ ew,
    float* __restrict__ out, int n_edges) {
  const long long idx = (long long)blockIdx.x * 256 + threadIdx.x;
  const int e = (int)(idx >> 6);
  const int c2 = (int)(idx & 63);
  if (e >= n_edges) return;
  const int s = esrc[e];
  const int d = edst[e];
  const float wt = ew[e];
  const uint u = *(const uint*)(sup + (size_t)s * NHID + c2 * 2);
  float* drow = out + (size_t)d * NHID + c2 * 2;
  atomicAdd(drow + 0, __uint_as_float(u << 16) * wt);
  atomicAdd(drow + 1, __uint_as_float(u & 0xffff0000u) * wt);
}

__global__ __launch_bounds__(256) void bias_relu_kernel(
    float* __restrict__ out, const float* __restrict__ b, int n4) {
  const int i = blockIdx.x * 256 + threadIdx.x;
  if (i >= n4) return;
  float4 v = ((float4*)out)[i];
  const float4 bb = ((const float4*)b)[i & (NHID / 4 - 1)];
  v.x = fmaxf(v.x + bb.x, 0.f);
  v.y = fmaxf(v.y + bb.y, 0.f);
  v.z = fmaxf(v.z + bb.z, 0.f);
  v.w = fmaxf(v.w + bb.w, 0.f);
  ((float4*)out)[i] = v;
}

static inline size_t align_up(size_t v, size_t a) { return (v + a - 1) & ~(a - 1); }

extern "C" void kernel_launch(void* const* d_in, const int* in_sizes, int n_in,
                              void* d_out, int out_size, void* d_ws, size_t ws_size,
                              hipStream_t stream) {
  const float* x    = (const float*)d_in[0];
  const int*   esrc = (const int*)d_in[1];
  const int*   edst = (const int*)d_in[2];
  const float* ew   = (const float*)d_in[3];
  const float* W    = (const float*)d_in[4];
  const float* b    = (const float*)d_in[5];
  float* out = (float*)d_out;

  const int n_nodes = in_sizes[0] / NFEAT;
  const int n_edges = in_sizes[1];

  // workspace layout (~46 MB at N=100k, E=1.6M)
  char* ws = (char*)d_ws;
  size_t off = 0;
  ushort* sup     = (ushort*)(ws + off); off = align_up(off + (size_t)n_nodes * NHID * 2, 256);
  ushort* Wt      = (ushort*)(ws + off); off = align_up(off + (size_t)NFEAT * NHID * 2, 256);
  int* counts     = (int*)(ws + off);    off = align_up(off + (size_t)n_nodes * 4, 256);
  int* exc        = (int*)(ws + off);    off = align_up(off + (size_t)n_nodes * 4, 256);
  int* bsums      = (int*)(ws + off);    off = align_up(off + 1024 * 4, 256);
  int* row_start  = (int*)(ws + off);    off = align_up(off + ((size_t)n_nodes + 1) * 4, 256);
  int* rank       = (int*)(ws + off);    off = align_up(off + (size_t)n_edges * 4, 256);
  int2* packed    = (int2*)(ws + off);   off = align_up(off + (size_t)n_edges * 8, 256);
  const bool csr_ok = (off <= ws_size) && (n_nodes <= 256 * 1024);

  // 1) Wt = bf16(W^T); support = bf16(x @ W) via MFMA
  wcvt_kernel<<<(NFEAT * NHID) / 256, 256, 0, stream>>>(W, Wt);
  gemm_mfma<<<(n_nodes + 63) / 64, 256, 0, stream>>>(x, Wt, sup, n_nodes);

  if (csr_ok) {
    // 2) CSR build (one atomic pass, rank-fused)
    hipMemsetAsync(counts, 0, (size_t)n_nodes * 4, stream);
    count_rank_kernel<<<(n_edges + 255) / 256, 256, 0, stream>>>(edst, counts, rank, n_edges);
    const int nb = (n_nodes + 1023) / 1024;
    scan1_kernel<<<nb, 256, 0, stream>>>(counts, exc, bsums, n_nodes);
    scan2_kernel<<<1, 256, 0, stream>>>(bsums, nb);
    scan3_kernel<<<(n_nodes + 255) / 256, 256, 0, stream>>>(exc, bsums, row_start, n_nodes, n_edges);
    fill_kernel<<<(n_edges + 255) / 256, 256, 0, stream>>>(esrc, edst, ew, rank, row_start, packed, n_edges);

    // 3) gather-sum + bias + relu
    agg_kernel<<<(n_nodes + 3) / 4, 256, 0, stream>>>(sup, (const i32x2*)packed, row_start, b, out, n_nodes);
  } else {
    hipMemsetAsync(out, 0, (size_t)n_nodes * NHID * sizeof(float), stream);
    const long long threads = (long long)n_edges * 64;
    scatter_bf16_kernel<<<(int)((threads + 255) / 256), 256, 0, stream>>>(sup, esrc, edst, ew, out, n_edges);
    const int n4 = n_nodes * NHID / 4;
    bias_relu_kernel<<<(n4 + 255) / 256, 256, 0, stream>>>(out, b, n4);
  }
}

// Round 5
// 195.620 us; speedup vs baseline: 14.4204x; 1.1524x over previous
//
#include <hip/hip_runtime.h>
#include <hip/hip_bf16.h>

#define NFEAT 256
#define NHID  128

typedef short s16x8 __attribute__((ext_vector_type(8)));
typedef float f32x4 __attribute__((ext_vector_type(4)));
typedef float f32x2 __attribute__((ext_vector_type(2)));

static __device__ __forceinline__ ushort bfbits(float f) {
  __hip_bfloat16 h = __float2bfloat16(f);
  return *reinterpret_cast<ushort*>(&h);
}

// ---------------------------------------------------------------------------
// W transpose+convert: Wt[n][k] = bf16(W[k][n])   (one-time, 32K elems)
// ---------------------------------------------------------------------------
__global__ __launch_bounds__(256) void wcvt_kernel(
    const float* __restrict__ W, ushort* __restrict__ Wt) {
  const int id = blockIdx.x * 256 + threadIdx.x;  // grid 128
  const int k = id >> 7, n = id & 127;            // coalesced read of W[k][n]
  Wt[n * NFEAT + k] = bfbits(W[id]);
}

// ---------------------------------------------------------------------------
// MFMA GEMM: support_bf16 = bf16(x @ W).  Block = 256 thr = 4 waves.
// Tile: BM=64 x NHID=128; K chunked by 64.  LDS XOR-swizzle (T2/G4).
// ---------------------------------------------------------------------------
__global__ __launch_bounds__(256) void gemm_mfma(
    const float* __restrict__ x, const ushort* __restrict__ Wt,
    ushort* __restrict__ sup, int n_nodes) {
  __shared__ ushort As[64 * 64];   // [r][k] swizzled, 8 KB
  __shared__ ushort Bs[128 * 64];  // [n][k] swizzled, 16 KB
  const int t = threadIdx.x;
  const int wid = t >> 6;
  const int lane = t & 63;
  const int rowBase = blockIdx.x * 64;

  f32x4 acc[4][2];
#pragma unroll
  for (int m = 0; m < 4; ++m)
#pragma unroll
    for (int n = 0; n < 2; ++n) acc[m][n] = (f32x4){0.f, 0.f, 0.f, 0.f};

  const float4* x4 = (const float4*)x;

  for (int kc = 0; kc < 4; ++kc) {
    __syncthreads();
#pragma unroll
    for (int it = 0; it < 4; ++it) {
      const int i4 = t + it * 256;
      const int r = i4 >> 4, k4 = i4 & 15;
      const int row = rowBase + r;
      float4 v = make_float4(0.f, 0.f, 0.f, 0.f);
      if (row < n_nodes) v = x4[(size_t)row * (NFEAT / 4) + kc * 16 + k4];
      ushort4 h;
      h.x = bfbits(v.x); h.y = bfbits(v.y); h.z = bfbits(v.z); h.w = bfbits(v.w);
      int byte = (r << 7) + (k4 << 3);
      byte ^= (r & 7) << 4;
      *(ushort4*)((char*)As + byte) = h;
    }
#pragma unroll
    for (int it = 0; it < 8; ++it) {
      const int idx = t + it * 256;
      const int col = idx >> 4, k4 = idx & 15;
      const ushort4 h = *(const ushort4*)(Wt + col * NFEAT + kc * 64 + k4 * 4);
      int byte = (col << 7) + (k4 << 3);
      byte ^= (col & 7) << 4;
      *(ushort4*)((char*)Bs + byte) = h;
    }
    __syncthreads();
#pragma unroll
    for (int ks = 0; ks < 2; ++ks) {
      const int k0 = ks * 32 + (lane >> 4) * 8;
      s16x8 af[4], bfr[2];
#pragma unroll
      for (int m = 0; m < 4; ++m) {
        const int r = m * 16 + (lane & 15);
        int byte = (r << 7) + (k0 << 1);
        byte ^= (r & 7) << 4;
        af[m] = *(const s16x8*)((const char*)As + byte);
      }
#pragma unroll
      for (int n = 0; n < 2; ++n) {
        const int c = wid * 32 + n * 16 + (lane & 15);
        int byte = (c << 7) + (k0 << 1);
        byte ^= (c & 7) << 4;
        bfr[n] = *(const s16x8*)((const char*)Bs + byte);
      }
#pragma unroll
      for (int m = 0; m < 4; ++m)
#pragma unroll
        for (int n = 0; n < 2; ++n)
          acc[m][n] = __builtin_amdgcn_mfma_f32_16x16x32_bf16(af[m], bfr[n], acc[m][n], 0, 0, 0);
    }
  }

  // C/D layout: col = lane&15, row = (lane>>4)*4 + reg   [m89-verified]
#pragma unroll
  for (int m = 0; m < 4; ++m) {
#pragma unroll
    for (int rr = 0; rr < 4; ++rr) {
      const int row = rowBase + m * 16 + (lane >> 4) * 4 + rr;
      if (row < n_nodes) {
#pragma unroll
        for (int n = 0; n < 2; ++n) {
          const int col = wid * 32 + n * 16 + (lane & 15);
          sup[(size_t)row * NHID + col] = bfbits(acc[m][n][rr]);
        }
      }
    }
  }
}

// ---------------------------------------------------------------------------
// CSR build: rank-fused histogram -> hierarchical scan -> atomic-free fill
// ---------------------------------------------------------------------------
__global__ __launch_bounds__(256) void count_rank_kernel(
    const int* __restrict__ edst, int* __restrict__ counts,
    int* __restrict__ rank, int n_edges) {
  const int e = blockIdx.x * 256 + threadIdx.x;
  if (e < n_edges) rank[e] = atomicAdd(&counts[edst[e]], 1);
}

__global__ __launch_bounds__(256) void scan1_kernel(
    const int* __restrict__ in, int* __restrict__ exc,
    int* __restrict__ bsums, int n) {
  const int tid = threadIdx.x;
  const int lane = tid & 63, wid = tid >> 6;
  const int base = blockIdx.x * 1024 + tid * 4;
  int v0 = 0, v1 = 0, v2 = 0, v3 = 0;
  if (base + 3 < n) {
    int4 v = *(const int4*)(in + base);
    v0 = v.x; v1 = v.y; v2 = v.z; v3 = v.w;
  } else {
    if (base + 0 < n) v0 = in[base + 0];
    if (base + 1 < n) v1 = in[base + 1];
    if (base + 2 < n) v2 = in[base + 2];
  }
  const int tsum = v0 + v1 + v2 + v3;
  int t = tsum;
#pragma unroll
  for (int d = 1; d < 64; d <<= 1) {
    int u = __shfl_up(t, d);
    if (lane >= d) t += u;
  }
  __shared__ int wtot[4], wpre[4];
  if (lane == 63) wtot[wid] = t;
  __syncthreads();
  if (tid == 0) {
    int s = 0;
    for (int w = 0; w < 4; ++w) { wpre[w] = s; s += wtot[w]; }
    bsums[blockIdx.x] = s;
  }
  __syncthreads();
  const int off = (t - tsum) + wpre[wid];
  if (base + 0 < n) exc[base + 0] = off;
  if (base + 1 < n) exc[base + 1] = off + v0;
  if (base + 2 < n) exc[base + 2] = off + v0 + v1;
  if (base + 3 < n) exc[base + 3] = off + v0 + v1 + v2;
}

__global__ __launch_bounds__(256) void scan2_kernel(int* __restrict__ bsums, int nb) {
  const int tid = threadIdx.x;
  const int lane = tid & 63, wid = tid >> 6;
  const int v = (tid < nb) ? bsums[tid] : 0;
  int t = v;
#pragma unroll
  for (int d = 1; d < 64; d <<= 1) {
    int u = __shfl_up(t, d);
    if (lane >= d) t += u;
  }
  __shared__ int wtot[4], wpre[4];
  if (lane == 63) wtot[wid] = t;
  __syncthreads();
  if (tid == 0) {
    int s = 0;
    for (int w = 0; w < 4; ++w) { wpre[w] = s; s += wtot[w]; }
  }
  __syncthreads();
  const int exc = (t - v) + wpre[wid];
  if (tid < nb) bsums[tid] = exc;
}

__global__ __launch_bounds__(256) void scan3_kernel(
    const int* __restrict__ exc, const int* __restrict__ bsums,
    int* __restrict__ row_start, int n, int n_edges) {
  const int i = blockIdx.x * 256 + threadIdx.x;
  if (i < n) row_start[i] = exc[i] + bsums[i >> 10];
  if (i == 0) row_start[n] = n_edges;
}

__global__ __launch_bounds__(256) void fill_kernel(
    const int* __restrict__ esrc, const int* __restrict__ edst,
    const float* __restrict__ ew, const int* __restrict__ rank,
    const int* __restrict__ row_start, int2* __restrict__ packed, int n_edges) {
  const int e = blockIdx.x * 256 + threadIdx.x;
  if (e >= n_edges) return;
  const int pos = row_start[edst[e]] + rank[e];
  packed[pos] = make_int2(esrc[e], __float_as_int(ew[e]));
}

// ---------------------------------------------------------------------------
// Aggregation: 1 wave per node; each lane owns 2 cols (uint = 2 bf16).
// start/end hoisted to SGPR via readfirstlane -> packed[] loads are
// wave-uniform (scalar s_load path, constant cache). Hand-unroll x4: 4
// independent 4B/lane gathers in flight, zero load->load dependence.
// Fused bias + ReLU, NT float2 store.
// ---------------------------------------------------------------------------
__global__ __launch_bounds__(256) void agg_kernel(
    const ushort* __restrict__ sup, const int2* __restrict__ packed,
    const int* __restrict__ row_start, const float* __restrict__ bias,
    float* __restrict__ out, int n_nodes) {
  const int node = blockIdx.x * 4 + (threadIdx.x >> 6);
  if (node >= n_nodes) return;
  const int lane = threadIdx.x & 63;
  const int start = __builtin_amdgcn_readfirstlane(row_start[node]);
  const int end   = __builtin_amdgcn_readfirstlane(row_start[node + 1]);

  float a0 = 0.f, a1 = 0.f, b0 = 0.f, b1 = 0.f;
  int i = start;
  for (; i + 3 < end; i += 4) {
    const int2 e0 = packed[i + 0];
    const int2 e1 = packed[i + 1];
    const int2 e2 = packed[i + 2];
    const int2 e3 = packed[i + 3];
    const uint u0 = *(const uint*)(sup + ((size_t)(uint)e0.x << 7) + lane * 2);
    const uint u1 = *(const uint*)(sup + ((size_t)(uint)e1.x << 7) + lane * 2);
    const uint u2 = *(const uint*)(sup + ((size_t)(uint)e2.x << 7) + lane * 2);
    const uint u3 = *(const uint*)(sup + ((size_t)(uint)e3.x << 7) + lane * 2);
    const float w0 = __int_as_float(e0.y);
    const float w1 = __int_as_float(e1.y);
    const float w2 = __int_as_float(e2.y);
    const float w3 = __int_as_float(e3.y);
    a0 += __uint_as_float(u0 << 16) * w0 + __uint_as_float(u2 << 16) * w2;
    a1 += __uint_as_float(u0 & 0xffff0000u) * w0 + __uint_as_float(u2 & 0xffff0000u) * w2;
    b0 += __uint_as_float(u1 << 16) * w1 + __uint_as_float(u3 << 16) * w3;
    b1 += __uint_as_float(u1 & 0xffff0000u) * w1 + __uint_as_float(u3 & 0xffff0000u) * w3;
  }
  for (; i < end; ++i) {
    const int2 e0 = packed[i];
    const uint u0 = *(const uint*)(sup + ((size_t)(uint)e0.x << 7) + lane * 2);
    const float w0 = __int_as_float(e0.y);
    a0 += __uint_as_float(u0 << 16) * w0;
    a1 += __uint_as_float(u0 & 0xffff0000u) * w0;
  }

  const float2 bb = ((const float2*)bias)[lane];
  f32x2 r;
  r.x = fmaxf(a0 + b0 + bb.x, 0.f);
  r.y = fmaxf(a1 + b1 + bb.y, 0.f);
  __builtin_nontemporal_store(r, (f32x2*)out + (size_t)node * (NHID / 2) + lane);
}

// ---------------------------------------------------------------------------
// Fallback (ws too small): atomic scatter over bf16 support
// ---------------------------------------------------------------------------
__global__ __launch_bounds__(256) void scatter_bf16_kernel(
    const ushort* __restrict__ sup, const int* __restrict__ esrc,
    const int* __restrict__ edst, const float* __restrict__ ew,
    float* __restrict__ out, int n_edges) {
  const long long idx = (long long)blockIdx.x * 256 + threadIdx.x;
  const int e = (int)(idx >> 6);
  const int c2 = (int)(idx & 63);
  if (e >= n_edges) return;
  const int s = esrc[e];
  const int d = edst[e];
  const float wt = ew[e];
  const uint u = *(const uint*)(sup + (size_t)s * NHID + c2 * 2);
  float* drow = out + (size_t)d * NHID + c2 * 2;
  atomicAdd(drow + 0, __uint_as_float(u << 16) * wt);
  atomicAdd(drow + 1, __uint_as_float(u & 0xffff0000u) * wt);
}

__global__ __launch_bounds__(256) void bias_relu_kernel(
    float* __restrict__ out, const float* __restrict__ b, int n4) {
  const int i = blockIdx.x * 256 + threadIdx.x;
  if (i >= n4) return;
  float4 v = ((float4*)out)[i];
  const float4 bb = ((const float4*)b)[i & (NHID / 4 - 1)];
  v.x = fmaxf(v.x + bb.x, 0.f);
  v.y = fmaxf(v.y + bb.y, 0.f);
  v.z = fmaxf(v.z + bb.z, 0.f);
  v.w = fmaxf(v.w + bb.w, 0.f);
  ((float4*)out)[i] = v;
}

static inline size_t align_up(size_t v, size_t a) { return (v + a - 1) & ~(a - 1); }

extern "C" void kernel_launch(void* const* d_in, const int* in_sizes, int n_in,
                              void* d_out, int out_size, void* d_ws, size_t ws_size,
                              hipStream_t stream) {
  const float* x    = (const float*)d_in[0];
  const int*   esrc = (const int*)d_in[1];
  const int*   edst = (const int*)d_in[2];
  const float* ew   = (const float*)d_in[3];
  const float* W    = (const float*)d_in[4];
  const float* b    = (const float*)d_in[5];
  float* out = (float*)d_out;

  const int n_nodes = in_sizes[0] / NFEAT;
  const int n_edges = in_sizes[1];

  // workspace layout (~46 MB at N=100k, E=1.6M)
  char* ws = (char*)d_ws;
  size_t off = 0;
  ushort* sup     = (ushort*)(ws + off); off = align_up(off + (size_t)n_nodes * NHID * 2, 256);
  ushort* Wt      = (ushort*)(ws + off); off = align_up(off + (size_t)NFEAT * NHID * 2, 256);
  int* counts     = (int*)(ws + off);    off = align_up(off + (size_t)n_nodes * 4, 256);
  int* exc        = (int*)(ws + off);    off = align_up(off + (size_t)n_nodes * 4, 256);
  int* bsums      = (int*)(ws + off);    off = align_up(off + 1024 * 4, 256);
  int* row_start  = (int*)(ws + off);    off = align_up(off + ((size_t)n_nodes + 1) * 4, 256);
  int* rank       = (int*)(ws + off);    off = align_up(off + (size_t)n_edges * 4, 256);
  int2* packed    = (int2*)(ws + off);   off = align_up(off + (size_t)n_edges * 8, 256);
  const bool csr_ok = (off <= ws_size) && (n_nodes <= 256 * 1024);

  // 1) Wt = bf16(W^T); support = bf16(x @ W) via MFMA
  wcvt_kernel<<<(NFEAT * NHID) / 256, 256, 0, stream>>>(W, Wt);
  gemm_mfma<<<(n_nodes + 63) / 64, 256, 0, stream>>>(x, Wt, sup, n_nodes);

  if (csr_ok) {
    // 2) CSR build (one atomic pass, rank-fused)
    hipMemsetAsync(counts, 0, (size_t)n_nodes * 4, stream);
    count_rank_kernel<<<(n_edges + 255) / 256, 256, 0, stream>>>(edst, counts, rank, n_edges);
    const int nb = (n_nodes + 1023) / 1024;
    scan1_kernel<<<nb, 256, 0, stream>>>(counts, exc, bsums, n_nodes);
    scan2_kernel<<<1, 256, 0, stream>>>(bsums, nb);
    scan3_kernel<<<(n_nodes + 255) / 256, 256, 0, stream>>>(exc, bsums, row_start, n_nodes, n_edges);
    fill_kernel<<<(n_edges + 255) / 256, 256, 0, stream>>>(esrc, edst, ew, rank, row_start, packed, n_edges);

    // 3) gather-sum + bias + relu
    agg_kernel<<<(n_nodes + 3) / 4, 256, 0, stream>>>(sup, packed, row_start, b, out, n_nodes);
  } else {
    hipMemsetAsync(out, 0, (size_t)n_nodes * NHID * sizeof(float), stream);
    const long long threads = (long long)n_edges * 64;
    scatter_bf16_kernel<<<(int)((threads + 255) / 256), 256, 0, stream>>>(sup, esrc, edst, ew, out, n_edges);
    const int n4 = n_nodes * NHID / 4;
    bias_relu_kernel<<<(n4 + 255) / 256, 256, 0, stream>>>(out, b, n4);
  }
}

// Round 6
// 192.682 us; speedup vs baseline: 14.6402x; 1.0152x over previous
//
#include <hip/hip_runtime.h>
#include <hip/hip_bf16.h>

#define NFEAT 256
#define NHID  128

typedef short s16x8 __attribute__((ext_vector_type(8)));
typedef float f32x4 __attribute__((ext_vector_type(4)));
typedef float f32x2 __attribute__((ext_vector_type(2)));

static __device__ __forceinline__ ushort bfbits(float f) {
  __hip_bfloat16 h = __float2bfloat16(f);
  return *reinterpret_cast<ushort*>(&h);
}

// ---------------------------------------------------------------------------
// Prep: blocks 0..127 convert W -> Wt (bf16, transposed); remaining blocks
// zero the counts array (replaces a separate hipMemsetAsync launch).
// ---------------------------------------------------------------------------
__global__ __launch_bounds__(256) void prep_kernel(
    const float* __restrict__ W, ushort* __restrict__ Wt,
    int* __restrict__ counts, int n_nodes) {
  if (blockIdx.x < 128) {
    const int id = blockIdx.x * 256 + threadIdx.x;
    const int k = id >> 7, n = id & 127;  // coalesced read of W[k][n]
    Wt[n * NFEAT + k] = bfbits(W[id]);
  } else {
    const int i = (blockIdx.x - 128) * 256 + threadIdx.x;
    if (i < n_nodes) counts[i] = 0;
  }
}

// ---------------------------------------------------------------------------
// Fused kernel: blocks [0, n_count_blocks) do the CSR count+rank pass
// (LLC-atomic-bound, ~0.5% VALU); remaining blocks run the MFMA GEMM
// (MFMA/LDS-bound).  Orthogonal resources -> concurrent execution hides the
// atomic latency under the GEMM.  Outputs disjoint; no inter-block deps.
// ---------------------------------------------------------------------------
__global__ __launch_bounds__(256) void gemm_count_fused(
    const float* __restrict__ x, const ushort* __restrict__ Wt,
    ushort* __restrict__ sup, int n_nodes,
    const int* __restrict__ edst, int* __restrict__ counts,
    int* __restrict__ rank, int n_edges, int n_count_blocks) {
  __shared__ ushort As[64 * 64];   // [r][k] swizzled, 8 KB
  __shared__ ushort Bs[128 * 64];  // [n][k] swizzled, 16 KB

  if ((int)blockIdx.x < n_count_blocks) {
    // ---- CSR count + rank (one with-return atomic per edge) ----
    const int e = blockIdx.x * 256 + threadIdx.x;
    if (e < n_edges) rank[e] = atomicAdd(&counts[edst[e]], 1);
    return;
  }

  // ---- MFMA GEMM: support_bf16 = bf16(x @ W), BM=64 x NHID=128 ----
  const int t = threadIdx.x;
  const int wid = t >> 6;
  const int lane = t & 63;
  const int rowBase = (blockIdx.x - n_count_blocks) * 64;
  if (rowBase >= n_nodes) return;

  f32x4 acc[4][2];
#pragma unroll
  for (int m = 0; m < 4; ++m)
#pragma unroll
    for (int n = 0; n < 2; ++n) acc[m][n] = (f32x4){0.f, 0.f, 0.f, 0.f};

  const float4* x4 = (const float4*)x;

  for (int kc = 0; kc < 4; ++kc) {
    __syncthreads();
#pragma unroll
    for (int it = 0; it < 4; ++it) {
      const int i4 = t + it * 256;
      const int r = i4 >> 4, k4 = i4 & 15;
      const int row = rowBase + r;
      float4 v = make_float4(0.f, 0.f, 0.f, 0.f);
      if (row < n_nodes) v = x4[(size_t)row * (NFEAT / 4) + kc * 16 + k4];
      ushort4 h;
      h.x = bfbits(v.x); h.y = bfbits(v.y); h.z = bfbits(v.z); h.w = bfbits(v.w);
      int byte = (r << 7) + (k4 << 3);
      byte ^= (r & 7) << 4;
      *(ushort4*)((char*)As + byte) = h;
    }
#pragma unroll
    for (int it = 0; it < 8; ++it) {
      const int idx = t + it * 256;
      const int col = idx >> 4, k4 = idx & 15;
      const ushort4 h = *(const ushort4*)(Wt + col * NFEAT + kc * 64 + k4 * 4);
      int byte = (col << 7) + (k4 << 3);
      byte ^= (col & 7) << 4;
      *(ushort4*)((char*)Bs + byte) = h;
    }
    __syncthreads();
#pragma unroll
    for (int ks = 0; ks < 2; ++ks) {
      const int k0 = ks * 32 + (lane >> 4) * 8;
      s16x8 af[4], bfr[2];
#pragma unroll
      for (int m = 0; m < 4; ++m) {
        const int r = m * 16 + (lane & 15);
        int byte = (r << 7) + (k0 << 1);
        byte ^= (r & 7) << 4;
        af[m] = *(const s16x8*)((const char*)As + byte);
      }
#pragma unroll
      for (int n = 0; n < 2; ++n) {
        const int c = wid * 32 + n * 16 + (lane & 15);
        int byte = (c << 7) + (k0 << 1);
        byte ^= (c & 7) << 4;
        bfr[n] = *(const s16x8*)((const char*)Bs + byte);
      }
#pragma unroll
      for (int m = 0; m < 4; ++m)
#pragma unroll
        for (int n = 0; n < 2; ++n)
          acc[m][n] = __builtin_amdgcn_mfma_f32_16x16x32_bf16(af[m], bfr[n], acc[m][n], 0, 0, 0);
    }
  }

  // C/D layout: col = lane&15, row = (lane>>4)*4 + reg   [m89-verified]
#pragma unroll
  for (int m = 0; m < 4; ++m) {
#pragma unroll
    for (int rr = 0; rr < 4; ++rr) {
      const int row = rowBase + m * 16 + (lane >> 4) * 4 + rr;
      if (row < n_nodes) {
#pragma unroll
        for (int n = 0; n < 2; ++n) {
          const int col = wid * 32 + n * 16 + (lane & 15);
          sup[(size_t)row * NHID + col] = bfbits(acc[m][n][rr]);
        }
      }
    }
  }
}

// ---------------------------------------------------------------------------
// Hierarchical exclusive scan over counts -> row_start
// ---------------------------------------------------------------------------
__global__ __launch_bounds__(256) void scan1_kernel(
    const int* __restrict__ in, int* __restrict__ exc,
    int* __restrict__ bsums, int n) {
  const int tid = threadIdx.x;
  const int lane = tid & 63, wid = tid >> 6;
  const int base = blockIdx.x * 1024 + tid * 4;
  int v0 = 0, v1 = 0, v2 = 0, v3 = 0;
  if (base + 3 < n) {
    int4 v = *(const int4*)(in + base);
    v0 = v.x; v1 = v.y; v2 = v.z; v3 = v.w;
  } else {
    if (base + 0 < n) v0 = in[base + 0];
    if (base + 1 < n) v1 = in[base + 1];
    if (base + 2 < n) v2 = in[base + 2];
  }
  const int tsum = v0 + v1 + v2 + v3;
  int t = tsum;
#pragma unroll
  for (int d = 1; d < 64; d <<= 1) {
    int u = __shfl_up(t, d);
    if (lane >= d) t += u;
  }
  __shared__ int wtot[4], wpre[4];
  if (lane == 63) wtot[wid] = t;
  __syncthreads();
  if (tid == 0) {
    int s = 0;
    for (int w = 0; w < 4; ++w) { wpre[w] = s; s += wtot[w]; }
    bsums[blockIdx.x] = s;
  }
  __syncthreads();
  const int off = (t - tsum) + wpre[wid];
  if (base + 0 < n) exc[base + 0] = off;
  if (base + 1 < n) exc[base + 1] = off + v0;
  if (base + 2 < n) exc[base + 2] = off + v0 + v1;
  if (base + 3 < n) exc[base + 3] = off + v0 + v1 + v2;
}

__global__ __launch_bounds__(256) void scan2_kernel(int* __restrict__ bsums, int nb) {
  const int tid = threadIdx.x;
  const int lane = tid & 63, wid = tid >> 6;
  const int v = (tid < nb) ? bsums[tid] : 0;
  int t = v;
#pragma unroll
  for (int d = 1; d < 64; d <<= 1) {
    int u = __shfl_up(t, d);
    if (lane >= d) t += u;
  }
  __shared__ int wtot[4], wpre[4];
  if (lane == 63) wtot[wid] = t;
  __syncthreads();
  if (tid == 0) {
    int s = 0;
    for (int w = 0; w < 4; ++w) { wpre[w] = s; s += wtot[w]; }
  }
  __syncthreads();
  const int exc = (t - v) + wpre[wid];
  if (tid < nb) bsums[tid] = exc;
}

__global__ __launch_bounds__(256) void scan3_kernel(
    const int* __restrict__ exc, const int* __restrict__ bsums,
    int* __restrict__ row_start, int n, int n_edges) {
  const int i = blockIdx.x * 256 + threadIdx.x;
  if (i < n) row_start[i] = exc[i] + bsums[i >> 10];
  if (i == 0) row_start[n] = n_edges;
}

__global__ __launch_bounds__(256) void fill_kernel(
    const int* __restrict__ esrc, const int* __restrict__ edst,
    const float* __restrict__ ew, const int* __restrict__ rank,
    const int* __restrict__ row_start, int2* __restrict__ packed, int n_edges) {
  const int e = blockIdx.x * 256 + threadIdx.x;
  if (e >= n_edges) return;
  const int pos = row_start[edst[e]] + rank[e];
  packed[pos] = make_int2(esrc[e], __float_as_int(ew[e]));
}

// ---------------------------------------------------------------------------
// Aggregation: 1 wave per node; lane owns 2 cols (uint = 2 bf16); SGPR-
// uniform packed loads; x4 unroll -> 4 independent gathers in flight.
// Fused bias + ReLU, NT float2 store.
// ---------------------------------------------------------------------------
__global__ __launch_bounds__(256) void agg_kernel(
    const ushort* __restrict__ sup, const int2* __restrict__ packed,
    const int* __restrict__ row_start, const float* __restrict__ bias,
    float* __restrict__ out, int n_nodes) {
  const int node = blockIdx.x * 4 + (threadIdx.x >> 6);
  if (node >= n_nodes) return;
  const int lane = threadIdx.x & 63;
  const int start = __builtin_amdgcn_readfirstlane(row_start[node]);
  const int end   = __builtin_amdgcn_readfirstlane(row_start[node + 1]);

  float a0 = 0.f, a1 = 0.f, b0 = 0.f, b1 = 0.f;
  int i = start;
  for (; i + 3 < end; i += 4) {
    const int2 e0 = packed[i + 0];
    const int2 e1 = packed[i + 1];
    const int2 e2 = packed[i + 2];
    const int2 e3 = packed[i + 3];
    const uint u0 = *(const uint*)(sup + ((size_t)(uint)e0.x << 7) + lane * 2);
    const uint u1 = *(const uint*)(sup + ((size_t)(uint)e1.x << 7) + lane * 2);
    const uint u2 = *(const uint*)(sup + ((size_t)(uint)e2.x << 7) + lane * 2);
    const uint u3 = *(const uint*)(sup + ((size_t)(uint)e3.x << 7) + lane * 2);
    const float w0 = __int_as_float(e0.y);
    const float w1 = __int_as_float(e1.y);
    const float w2 = __int_as_float(e2.y);
    const float w3 = __int_as_float(e3.y);
    a0 += __uint_as_float(u0 << 16) * w0 + __uint_as_float(u2 << 16) * w2;
    a1 += __uint_as_float(u0 & 0xffff0000u) * w0 + __uint_as_float(u2 & 0xffff0000u) * w2;
    b0 += __uint_as_float(u1 << 16) * w1 + __uint_as_float(u3 << 16) * w3;
    b1 += __uint_as_float(u1 & 0xffff0000u) * w1 + __uint_as_float(u3 & 0xffff0000u) * w3;
  }
  for (; i < end; ++i) {
    const int2 e0 = packed[i];
    const uint u0 = *(const uint*)(sup + ((size_t)(uint)e0.x << 7) + lane * 2);
    const float w0 = __int_as_float(e0.y);
    a0 += __uint_as_float(u0 << 16) * w0;
    a1 += __uint_as_float(u0 & 0xffff0000u) * w0;
  }

  const float2 bb = ((const float2*)bias)[lane];
  f32x2 r;
  r.x = fmaxf(a0 + b0 + bb.x, 0.f);
  r.y = fmaxf(a1 + b1 + bb.y, 0.f);
  __builtin_nontemporal_store(r, (f32x2*)out + (size_t)node * (NHID / 2) + lane);
}

// ---------------------------------------------------------------------------
// Fallback (ws too small): atomic scatter over bf16 support
// ---------------------------------------------------------------------------
__global__ __launch_bounds__(256) void scatter_bf16_kernel(
    const ushort* __restrict__ sup, const int* __restrict__ esrc,
    const int* __restrict__ edst, const float* __restrict__ ew,
    float* __restrict__ out, int n_edges) {
  const long long idx = (long long)blockIdx.x * 256 + threadIdx.x;
  const int e = (int)(idx >> 6);
  const int c2 = (int)(idx & 63);
  if (e >= n_edges) return;
  const int s = esrc[e];
  const int d = edst[e];
  const float wt = ew[e];
  const uint u = *(const uint*)(sup + (size_t)s * NHID + c2 * 2);
  float* drow = out + (size_t)d * NHID + c2 * 2;
  atomicAdd(drow + 0, __uint_as_float(u << 16) * wt);
  atomicAdd(drow + 1, __uint_as_float(u & 0xffff0000u) * wt);
}

__global__ __launch_bounds__(256) void bias_relu_kernel(
    float* __restrict__ out, const float* __restrict__ b, int n4) {
  const int i = blockIdx.x * 256 + threadIdx.x;
  if (i >= n4) return;
  float4 v = ((float4*)out)[i];
  const float4 bb = ((const float4*)b)[i & (NHID / 4 - 1)];
  v.x = fmaxf(v.x + bb.x, 0.f);
  v.y = fmaxf(v.y + bb.y, 0.f);
  v.z = fmaxf(v.z + bb.z, 0.f);
  v.w = fmaxf(v.w + bb.w, 0.f);
  ((float4*)out)[i] = v;
}

static inline size_t align_up(size_t v, size_t a) { return (v + a - 1) & ~(a - 1); }

extern "C" void kernel_launch(void* const* d_in, const int* in_sizes, int n_in,
                              void* d_out, int out_size, void* d_ws, size_t ws_size,
                              hipStream_t stream) {
  const float* x    = (const float*)d_in[0];
  const int*   esrc = (const int*)d_in[1];
  const int*   edst = (const int*)d_in[2];
  const float* ew   = (const float*)d_in[3];
  const float* W    = (const float*)d_in[4];
  const float* b    = (const float*)d_in[5];
  float* out = (float*)d_out;

  const int n_nodes = in_sizes[0] / NFEAT;
  const int n_edges = in_sizes[1];

  // workspace layout (~46 MB at N=100k, E=1.6M)
  char* ws = (char*)d_ws;
  size_t off = 0;
  ushort* sup     = (ushort*)(ws + off); off = align_up(off + (size_t)n_nodes * NHID * 2, 256);
  ushort* Wt      = (ushort*)(ws + off); off = align_up(off + (size_t)NFEAT * NHID * 2, 256);
  int* counts     = (int*)(ws + off);    off = align_up(off + (size_t)n_nodes * 4, 256);
  int* exc        = (int*)(ws + off);    off = align_up(off + (size_t)n_nodes * 4, 256);
  int* bsums      = (int*)(ws + off);    off = align_up(off + 1024 * 4, 256);
  int* row_start  = (int*)(ws + off);    off = align_up(off + ((size_t)n_nodes + 1) * 4, 256);
  int* rank       = (int*)(ws + off);    off = align_up(off + (size_t)n_edges * 4, 256);
  int2* packed    = (int2*)(ws + off);   off = align_up(off + (size_t)n_edges * 8, 256);
  const bool csr_ok = (off <= ws_size) && (n_nodes <= 256 * 1024);

  // 1) prep: Wt = bf16(W^T), counts = 0 (one launch)
  prep_kernel<<<128 + (n_nodes + 255) / 256, 256, 0, stream>>>(W, Wt, counts, n_nodes);

  if (csr_ok) {
    // 2) fused: GEMM (MFMA) || CSR count+rank (LLC atomics) — overlapped
    const int n_count_blocks = (n_edges + 255) / 256;
    const int n_gemm_blocks = (n_nodes + 63) / 64;
    gemm_count_fused<<<n_count_blocks + n_gemm_blocks, 256, 0, stream>>>(
        x, Wt, sup, n_nodes, edst, counts, rank, n_edges, n_count_blocks);

    // 3) scan + fill
    const int nb = (n_nodes + 1023) / 1024;
    scan1_kernel<<<nb, 256, 0, stream>>>(counts, exc, bsums, n_nodes);
    scan2_kernel<<<1, 256, 0, stream>>>(bsums, nb);
    scan3_kernel<<<(n_nodes + 255) / 256, 256, 0, stream>>>(exc, bsums, row_start, n_nodes, n_edges);
    fill_kernel<<<(n_edges + 255) / 256, 256, 0, stream>>>(esrc, edst, ew, rank, row_start, packed, n_edges);

    // 4) gather-sum + bias + relu
    agg_kernel<<<(n_nodes + 3) / 4, 256, 0, stream>>>(sup, packed, row_start, b, out, n_nodes);
  } else {
    // fallback: plain GEMM (gemm blocks only) + atomic scatter
    gemm_count_fused<<<(n_nodes + 63) / 64, 256, 0, stream>>>(
        x, Wt, sup, n_nodes, edst, counts, rank, 0, 0);
    hipMemsetAsync(out, 0, (size_t)n_nodes * NHID * sizeof(float), stream);
    const long long threads = (long long)n_edges * 64;
    scatter_bf16_kernel<<<(int)((threads + 255) / 256), 256, 0, stream>>>(sup, esrc, edst, ew, out, n_edges);
    const int n4 = n_nodes * NHID / 4;
    bias_relu_kernel<<<(n4 + 255) / 256, 256, 0, stream>>>(out, b, n4);
  }
}